// Round 20
// baseline (106.479 us; speedup 1.0000x reference)
//
#include <hip/hip_runtime.h>
#include <hip/hip_bf16.h>

#define T_ 8
#define H_ 96
#define W_ 160
#define C_ 256
#define F_ 256
#define M_ (T_ * H_ * W_)   // 122880

typedef __bf16 bf16_t;
typedef __bf16 bf16x2 __attribute__((ext_vector_type(2)));
typedef __bf16 bf16x8 __attribute__((ext_vector_type(8)));
typedef float  f32x4  __attribute__((ext_vector_type(4)));

// ---------------- pass 0: WpT[f][c] = bf16(Wp[c][f]) ----------------
__global__ void wp_transpose_kernel(const float* __restrict__ Wp,
                                    bf16_t* __restrict__ WpT) {
    int c = blockIdx.x;   // 0..255
    int f = threadIdx.x;  // 0..255
    WpT[f * C_ + c] = (bf16_t)Wp[c * F_ + f];
}

// ---------------- pass 1: depthwise 3x3x3, rolling 12-h strip, w-pair, scalar --
// Two-term law: dur = 0.0336*I[k-wave-instr] + 0.0976*B[MB requested].
// r19 change: intermediate stored W-PAIR-INTERLEAVED — dw2[g][c][iw] with
// g=(t*H+h)*80+wp — so each thread stores 96 bf16x2 (256B/wave, full
// coalescing) instead of 192 scalar bf16 (128B/wave). ~-246k wave-instrs.
// GEMM de-interleaves during its LDS A-stage (row m = (g=m>>1, iw=m&1)).
#define PLANE(I)                                                              \
  {                                                                           \
    const int hh = h0 + (I) - 1;                                              \
    float v[4][8];                                                            \
    _Pragma("unroll") for (int j = 0; j < 4; ++j)                             \
      _Pragma("unroll") for (int tt = 0; tt < 8; ++tt) v[j][tt] = 0.f;        \
    if (hh >= 0 && hh < H_) {            /* block-uniform */                  \
      const float* pb = x + (((long)hh * W_ + w0) * C_ + c);                  \
      _Pragma("unroll") for (int tt = 0; tt < 8; ++tt)                        \
        v[1][tt] = pb[(long)tt * tstride];                                    \
      _Pragma("unroll") for (int tt = 0; tt < 8; ++tt)                        \
        v[2][tt] = pb[C_ + (long)tt * tstride];                               \
      if (hasL) {                                                             \
        _Pragma("unroll") for (int tt = 0; tt < 8; ++tt)                      \
          v[0][tt] = pb[-C_ + (long)tt * tstride];                            \
      }                                                                       \
      if (hasR) {                                                             \
        _Pragma("unroll") for (int tt = 0; tt < 8; ++tt)                      \
          v[3][tt] = pb[2 * C_ + (long)tt * tstride];                         \
      }                                                                       \
    }                                                                         \
    _Pragma("unroll") for (int kh = 0; kh < 3; ++kh) {                        \
      const int ko = (I) - kh;           /* literal after unroll */           \
      if (ko >= 0 && ko <= 11) {                                              \
        _Pragma("unroll") for (int to = 0; to < 8; ++to) {                    \
          float s0 = 0.f, s1 = 0.f;                                           \
          _Pragma("unroll") for (int kt = 0; kt < 3; ++kt) {                  \
            const int ti = to + kt - 1;                                       \
            if (ti >= 0 && ti < 8) {                                          \
              _Pragma("unroll") for (int kw = 0; kw < 3; ++kw) {              \
                const float wv = wreg[(kt * 3 + kh) * 3 + kw];                \
                s0 += v[kw][ti] * wv;                                         \
                s1 += v[kw + 1][ti] * wv;                                     \
              }                                                               \
            }                                                                 \
          }                                                                   \
          if (kh == 0) { acc[ko][to][0] = s0;  acc[ko][to][1] = s1; }         \
          else         { acc[ko][to][0] += s0; acc[ko][to][1] += s1; }        \
        }                                                                     \
      }                                                                       \
    }                                                                         \
    const int kd = (I) - 2;                                                   \
    if (kd >= 0 && kd <= 11) {                                                \
      _Pragma("unroll") for (int tt = 0; tt < 8; ++tt) {                      \
        const long g = (long)(tt * H_ + h0 + kd) * (W_ / 2) + wp;             \
        bf16x2 o;                                                             \
        o[0] = (bf16_t)acc[kd][tt][0];                                        \
        o[1] = (bf16_t)acc[kd][tt][1];                                        \
        *(bf16x2*)&dw2[g * (C_ * 2) + c * 2] = o;                             \
      }                                                                       \
    }                                                                         \
  }

__global__ __launch_bounds__(128, 2) void dw_conv_kernel(const float* __restrict__ x,
                                                         const float* __restrict__ Wd,
                                                         bf16_t* __restrict__ dw2) {
    // XCD-chunked swizzle: grid 1280 % 8 == 0 -> bijective
    int nchunk = gridDim.x >> 3;
    int bb  = (blockIdx.x & 7) * nchunk + (blockIdx.x >> 3);
    // c-half innermost: spatially adjacent blocks stay adjacent for L2 halos
    int ch  = bb & 1;
    int sp  = bb >> 1;               // 0..639
    int hs  = sp / (W_ / 2);         // strip, 0..7
    int wp  = sp % (W_ / 2);         // w-pair, 0..79
    int h0  = hs * 12;
    int w0  = wp * 2;                // outputs {w0, w0+1}
    int c   = ch * 128 + threadIdx.x;

    const bool hasL = (w0 > 0);          // block-uniform
    const bool hasR = (w0 + 2 < W_);     // block-uniform
    const int tstride = H_ * W_ * C_;

    float wreg[27];
#pragma unroll
    for (int k = 0; k < 27; ++k) wreg[k] = Wd[k * C_ + c];

    float acc[12][8][2];             // [h-out][t][iw]; live window <= 3 h-sets

    PLANE(0)  PLANE(1)  PLANE(2)  PLANE(3)  PLANE(4)  PLANE(5)  PLANE(6)
    PLANE(7)  PLANE(8)  PLANE(9)  PLANE(10) PLANE(11) PLANE(12) PLANE(13)
}

// ---------------- pass 2: GEMM [M,256]x[256,256] bf16 MFMA + ReLU ----------------
// A source is w-pair-interleaved: bf16 index g*512 + c*2 + iw, m = g*2 + iw.
// Staging de-interleaves one uint4 (4c x 2iw) into rows 2g / 2g+1 via
// even/odd short extraction (6 bit-ops), two 8B LDS writes.
#define BM 128
#define BN 256
#define BK 32
#define LDSTR 40  // 32 + 8 pad: fragment ds_read_b128 2-way (free) instead of 8-way

__global__ __launch_bounds__(512) void gemm_kernel(const bf16_t* __restrict__ A2,  // dw2, interleaved
                                                   const bf16_t* __restrict__ Bt,  // WpT [F][C] (n-major)
                                                   float* __restrict__ out) {      // [M][F]
    __shared__ __align__(16) bf16_t As[BM * LDSTR];
    __shared__ __align__(16) bf16_t Bs[BN * LDSTR];

    int m0   = blockIdx.x * BM;
    int g0   = blockIdx.x * (BM / 2);  // 64 g-groups per block
    int tid  = threadIdx.x;
    int lane = tid & 63;
    int wid  = tid >> 6;   // 0..7
    int wr   = wid >> 2;   // 0..1  (m-half)
    int wc   = wid & 3;    // 0..3  (f-quarter)
    int r16  = lane & 15;
    int kg   = lane >> 4;  // 0..3

    f32x4 acc[4][4] = {};

    for (int k0 = 0; k0 < C_; k0 += BK) {
        __syncthreads();
        // stage A tile [128 x 32] from interleaved source: 512 units, 1/thread
        {
            int gq = tid >> 3;           // 0..63
            int q  = tid & 7;            // k-quad (4 channels)
            const uint4 va = *(const uint4*)&A2[(long)(g0 + gq) * (C_ * 2) + (k0 + q * 4) * 2];
            uint e0 = (va.x & 0xFFFFu) | (va.y << 16);
            uint e1 = (va.z & 0xFFFFu) | (va.w << 16);
            uint o0 = (va.x >> 16) | (va.y & 0xFFFF0000u);
            uint o1 = (va.z >> 16) | (va.w & 0xFFFF0000u);
            uint2* pe = (uint2*)&As[(2 * gq + 0) * LDSTR + q * 4];
            uint2* po = (uint2*)&As[(2 * gq + 1) * LDSTR + q * 4];
            *pe = uint2{e0, e1};
            *po = uint2{o0, o1};
        }
        // stage B tile [256 x 32]: 1024 slots, 2 per thread
#pragma unroll
        for (int it = 0; it < 2; ++it) {
            int slot = tid + it * 512;
            int row  = slot >> 2, seg = slot & 3;
            uint4 vb = *(const uint4*)&Bt[(long)row * C_ + k0 + seg * 8];
            *(uint4*)&Bs[row * LDSTR + seg * 8] = vb;
        }
        __syncthreads();

        bf16x8 af[4], bfr[4];
#pragma unroll
        for (int m = 0; m < 4; ++m)
            af[m] = *(const bf16x8*)&As[(wr * 64 + m * 16 + r16) * LDSTR + kg * 8];
#pragma unroll
        for (int n = 0; n < 4; ++n)
            bfr[n] = *(const bf16x8*)&Bs[(wc * 64 + n * 16 + r16) * LDSTR + kg * 8];

#pragma unroll
        for (int m = 0; m < 4; ++m)
#pragma unroll
            for (int n = 0; n < 4; ++n)
                acc[m][n] = __builtin_amdgcn_mfma_f32_16x16x32_bf16(af[m], bfr[n], acc[m][n], 0, 0, 0);
    }

    // epilogue: ReLU + fp32 store.  D layout: row=(l>>4)*4+r, col=l&15
    int rbase = m0 + wr * 64 + kg * 4;
    int cbase = wc * 64 + r16;
#pragma unroll
    for (int m = 0; m < 4; ++m)
#pragma unroll
        for (int n = 0; n < 4; ++n)
#pragma unroll
            for (int r = 0; r < 4; ++r) {
                float v = acc[m][n][r];
                v = v > 0.f ? v : 0.f;
                out[(long)(rbase + m * 16 + r) * F_ + cbase + n * 16] = v;
            }
}

extern "C" void kernel_launch(void* const* d_in, const int* in_sizes, int n_in,
                              void* d_out, int out_size, void* d_ws, size_t ws_size,
                              hipStream_t stream) {
    const float* x  = (const float*)d_in[0];
    const float* Wd = (const float*)d_in[1];
    const float* Wp = (const float*)d_in[2];
    float* out = (float*)d_out;

    bf16_t* dw2 = (bf16_t*)d_ws;                                  // M_*C_ bf16 = 62,914,560 B
    bf16_t* WpT = (bf16_t*)((char*)d_ws + (size_t)M_ * C_ * 2);   // + 131,072 B

    wp_transpose_kernel<<<C_, F_, 0, stream>>>(Wp, WpT);
    dw_conv_kernel<<<(H_ / 12) * (W_ / 2) * 2, 128, 0, stream>>>(x, Wd, dw2);
    gemm_kernel<<<M_ / BM, 512, 0, stream>>>(dw2, WpT, out);
}

// Round 21
// 99.225 us; speedup vs baseline: 1.0731x; 1.0731x over previous
//
#include <hip/hip_runtime.h>
#include <hip/hip_bf16.h>

#define T_ 8
#define H_ 96
#define W_ 160
#define C_ 256
#define F_ 256
#define M_ (T_ * H_ * W_)   // 122880

typedef __bf16 bf16_t;
typedef __bf16 bf16x8 __attribute__((ext_vector_type(8)));
typedef float  f32x4  __attribute__((ext_vector_type(4)));

// ---------------- pass 0: WpT[f][c] = bf16(Wp[c][f]) ----------------
__global__ void wp_transpose_kernel(const float* __restrict__ Wp,
                                    bf16_t* __restrict__ WpT) {
    int c = blockIdx.x;   // 0..255
    int f = threadIdx.x;  // 0..255
    WpT[f * C_ + c] = (bf16_t)Wp[c * F_ + f];
}

// ---------------- pass 1: depthwise 3x3x3, rolling 12-h strip, w-pair, scalar --
// Two-term law: dur = 0.0336*I[k-wave-instr] + 0.0976*B[MB requested], with
// coefficient degradation below ~10 waves/CU. Strip-12: grid 1280 -> 10 w/CU,
// I=1147k, B=294MB -> ~66us measured (r19). Constraints that define this
// optimum: c-in-lanes (coalescing), no LDS staging (serialization, r9/r12),
// live VGPR <= ~90 (spill/occupancy cliff, r5/r14/r16/r20).
#define PLANE(I)                                                              \
  {                                                                           \
    const int hh = h0 + (I) - 1;                                              \
    float v[4][8];                                                            \
    _Pragma("unroll") for (int j = 0; j < 4; ++j)                             \
      _Pragma("unroll") for (int tt = 0; tt < 8; ++tt) v[j][tt] = 0.f;        \
    if (hh >= 0 && hh < H_) {            /* block-uniform */                  \
      const float* pb = x + (((long)hh * W_ + w0) * C_ + c);                  \
      _Pragma("unroll") for (int tt = 0; tt < 8; ++tt)                        \
        v[1][tt] = pb[(long)tt * tstride];                                    \
      _Pragma("unroll") for (int tt = 0; tt < 8; ++tt)                        \
        v[2][tt] = pb[C_ + (long)tt * tstride];                               \
      if (hasL) {                                                             \
        _Pragma("unroll") for (int tt = 0; tt < 8; ++tt)                      \
          v[0][tt] = pb[-C_ + (long)tt * tstride];                            \
      }                                                                       \
      if (hasR) {                                                             \
        _Pragma("unroll") for (int tt = 0; tt < 8; ++tt)                      \
          v[3][tt] = pb[2 * C_ + (long)tt * tstride];                         \
      }                                                                       \
    }                                                                         \
    _Pragma("unroll") for (int kh = 0; kh < 3; ++kh) {                        \
      const int ko = (I) - kh;           /* literal after unroll */           \
      if (ko >= 0 && ko <= 11) {                                              \
        _Pragma("unroll") for (int to = 0; to < 8; ++to) {                    \
          float s0 = 0.f, s1 = 0.f;                                           \
          _Pragma("unroll") for (int kt = 0; kt < 3; ++kt) {                  \
            const int ti = to + kt - 1;                                       \
            if (ti >= 0 && ti < 8) {                                          \
              _Pragma("unroll") for (int kw = 0; kw < 3; ++kw) {              \
                const float wv = wreg[(kt * 3 + kh) * 3 + kw];                \
                s0 += v[kw][ti] * wv;                                         \
                s1 += v[kw + 1][ti] * wv;                                     \
              }                                                               \
            }                                                                 \
          }                                                                   \
          if (kh == 0) { acc[ko][to][0] = s0;  acc[ko][to][1] = s1; }         \
          else         { acc[ko][to][0] += s0; acc[ko][to][1] += s1; }        \
        }                                                                     \
      }                                                                       \
    }                                                                         \
    const int kd = (I) - 2;                                                   \
    if (kd >= 0 && kd <= 11) {                                                \
      _Pragma("unroll") for (int tt = 0; tt < 8; ++tt) {                      \
        bf16_t* pd = &dw[(((long)tt * H_ + h0 + kd) * W_ + w0) * C_ + c];     \
        pd[0]  = (bf16_t)acc[kd][tt][0];                                      \
        pd[C_] = (bf16_t)acc[kd][tt][1];                                      \
      }                                                                       \
    }                                                                         \
  }

__global__ __launch_bounds__(128, 2) void dw_conv_kernel(const float* __restrict__ x,
                                                         const float* __restrict__ Wd,
                                                         bf16_t* __restrict__ dw) {
    // XCD-chunked swizzle: grid 1280 % 8 == 0 -> bijective
    int nchunk = gridDim.x >> 3;
    int bb  = (blockIdx.x & 7) * nchunk + (blockIdx.x >> 3);
    // c-half innermost: spatially adjacent blocks stay adjacent for L2 halos
    int ch  = bb & 1;
    int sp  = bb >> 1;               // 0..639
    int hs  = sp / (W_ / 2);         // strip, 0..7
    int wp  = sp % (W_ / 2);         // w-pair, 0..79
    int h0  = hs * 12;
    int w0  = wp * 2;                // outputs {w0, w0+1}
    int c   = ch * 128 + threadIdx.x;

    const bool hasL = (w0 > 0);          // block-uniform
    const bool hasR = (w0 + 2 < W_);     // block-uniform
    const int tstride = H_ * W_ * C_;

    float wreg[27];
#pragma unroll
    for (int k = 0; k < 27; ++k) wreg[k] = Wd[k * C_ + c];

    float acc[12][8][2];             // [h-out][t][iw]; live window <= 3 h-sets

    PLANE(0)  PLANE(1)  PLANE(2)  PLANE(3)  PLANE(4)  PLANE(5)  PLANE(6)
    PLANE(7)  PLANE(8)  PLANE(9)  PLANE(10) PLANE(11) PLANE(12) PLANE(13)
}

// ---------------- pass 2: GEMM [M,256]x[256,256] bf16 MFMA + ReLU ----------------
// BN=256 (full F per block) kills the 2x A-re-read: requests 378 -> 315 MB.
// 512 threads, 8 waves = 2(m) x 4(f); per-wave shape identical to the proven
// 64x64 kernel (4 A-frags x 4 B-frags), only staging/indexing relabeled.
#define BM 128
#define BN 256
#define BK 32
#define LDSTR 40  // 32 + 8 pad: fragment ds_read_b128 2-way (free) instead of 8-way

__global__ __launch_bounds__(512) void gemm_kernel(const bf16_t* __restrict__ A,   // dw  [M][C]
                                                   const bf16_t* __restrict__ Bt,  // WpT [F][C] (n-major)
                                                   float* __restrict__ out) {      // [M][F]
    __shared__ __align__(16) bf16_t As[BM * LDSTR];
    __shared__ __align__(16) bf16_t Bs[BN * LDSTR];

    int m0   = blockIdx.x * BM;
    int tid  = threadIdx.x;
    int lane = tid & 63;
    int wid  = tid >> 6;   // 0..7
    int wr   = wid >> 2;   // 0..1  (m-half)
    int wc   = wid & 3;    // 0..3  (f-quarter)
    int r16  = lane & 15;
    int kg   = lane >> 4;  // 0..3

    f32x4 acc[4][4] = {};

    for (int k0 = 0; k0 < C_; k0 += BK) {
        __syncthreads();
        // stage A tile [128 x 32]: 512 slots, 1 per thread
        {
            int row = tid >> 2, seg = tid & 3;
            uint4 va = *(const uint4*)&A[(long)(m0 + row) * C_ + k0 + seg * 8];
            *(uint4*)&As[row * LDSTR + seg * 8] = va;
        }
        // stage B tile [256 x 32]: 1024 slots, 2 per thread
#pragma unroll
        for (int it = 0; it < 2; ++it) {
            int slot = tid + it * 512;
            int row  = slot >> 2, seg = slot & 3;
            uint4 vb = *(const uint4*)&Bt[(long)row * C_ + k0 + seg * 8];
            *(uint4*)&Bs[row * LDSTR + seg * 8] = vb;
        }
        __syncthreads();

        bf16x8 af[4], bfr[4];
#pragma unroll
        for (int m = 0; m < 4; ++m)
            af[m] = *(const bf16x8*)&As[(wr * 64 + m * 16 + r16) * LDSTR + kg * 8];
#pragma unroll
        for (int n = 0; n < 4; ++n)
            bfr[n] = *(const bf16x8*)&Bs[(wc * 64 + n * 16 + r16) * LDSTR + kg * 8];

#pragma unroll
        for (int m = 0; m < 4; ++m)
#pragma unroll
            for (int n = 0; n < 4; ++n)
                acc[m][n] = __builtin_amdgcn_mfma_f32_16x16x32_bf16(af[m], bfr[n], acc[m][n], 0, 0, 0);
    }

    // epilogue: ReLU + fp32 store.  D layout: row=(l>>4)*4+r, col=l&15
    int rbase = m0 + wr * 64 + kg * 4;
    int cbase = wc * 64 + r16;
#pragma unroll
    for (int m = 0; m < 4; ++m)
#pragma unroll
        for (int n = 0; n < 4; ++n)
#pragma unroll
            for (int r = 0; r < 4; ++r) {
                float v = acc[m][n][r];
                v = v > 0.f ? v : 0.f;
                out[(long)(rbase + m * 16 + r) * F_ + cbase + n * 16] = v;
            }
}

extern "C" void kernel_launch(void* const* d_in, const int* in_sizes, int n_in,
                              void* d_out, int out_size, void* d_ws, size_t ws_size,
                              hipStream_t stream) {
    const float* x  = (const float*)d_in[0];
    const float* Wd = (const float*)d_in[1];
    const float* Wp = (const float*)d_in[2];
    float* out = (float*)d_out;

    bf16_t* dw  = (bf16_t*)d_ws;                                  // M_*C_ bf16 = 62,914,560 B
    bf16_t* WpT = (bf16_t*)((char*)d_ws + (size_t)M_ * C_ * 2);   // + 131,072 B

    wp_transpose_kernel<<<C_, F_, 0, stream>>>(Wp, WpT);
    dw_conv_kernel<<<(H_ / 12) * (W_ / 2) * 2, 128, 0, stream>>>(x, Wd, dw);
    gemm_kernel<<<M_ / BM, 512, 0, stream>>>(dw, WpT, out);
}